// Round 4
// baseline (33.168 us; speedup 1.0000x reference)
//
#include <hip/hip_runtime.h>

#define B_   4
#define L_   1024
#define D_   16
#define H_   32
#define TAU_ 64
#define EMB_ 8

// ---------------------------------------------------------------------------
// Single fused kernel. Grid (L/64 j-tiles, L/64 i-tiles, B), 256 thr = 4 waves.
// Phase 1: block computes its own ai tile (rows i0..i0+63), aj tile (rows
//          j0..j0+63) from x @ W1 splits, staged in LDS. 2 threads/row,
//          16 h each, 256 fma/thread. Band blocks also build the 65x32
//          ae table (8 fma x ~8 entries/thread); const blocks build one row.
// Phase 2: lane = j offset (coalesced stores); wave w owns rows i0+w*16..+15.
//          ai rows are wave-uniform -> LDS broadcast ds_read_b128 (stride 32,
//          conflict-free by uniformity). aj per-lane from stride-33 LDS.
// ---------------------------------------------------------------------------
__global__ __launch_bounds__(256, 4) void fused_bias_kernel(
    const float* __restrict__ x,  const float* __restrict__ dtt,
    const float* __restrict__ W1, const float* __restrict__ b1,
    const float* __restrict__ W2, const float* __restrict__ b2p,
    float* __restrict__ out)
{
    __shared__ float ai_lds[64 * 32];            // 8 KB, broadcast-read rows
    __shared__ float aj_lds[64 * 33];            // 8.25 KB, per-lane reads
    __shared__ float ae_lds[(TAU_ + 1) * 33];    // 8.6 KB, band blocks only
    __shared__ float aec[H_];                    // const-dt ae row

    const int b    = blockIdx.z;
    const int i0   = blockIdx.y * 64;
    const int j0   = blockIdx.x * 64;
    const int tid  = threadIdx.x;
    const int lane = tid & 63;
    const int w    = __builtin_amdgcn_readfirstlane(tid >> 6);
    const int j    = j0 + lane;

    const bool c0   = (j0 >= i0 + 64);           // dt == 0 over whole tile
    const bool c64  = (i0 >= j0 + 128);          // dt == 64 over whole tile
    const bool constpath = c0 || c64;

    // ---- Phase 1a: ai/aj tiles (x[row,:16] @ W1 halves). ----
    {
        const int g    = tid >> 7;               // 0 = ai (i-rows), 1 = aj (j-rows)
        const int t    = tid & 127;
        const int row  = t >> 1;
        const int half = t & 1;
        const int grow = (g ? j0 : i0) + row;

        const float4* xr = (const float4*)(x + ((size_t)(b * L_ + grow)) * D_);
        const float4 x0 = xr[0], x1 = xr[1], x2 = xr[2], x3 = xr[3];
        const float xv[D_] = {x0.x, x0.y, x0.z, x0.w, x1.x, x1.y, x1.z, x1.w,
                              x2.x, x2.y, x2.z, x2.w, x3.x, x3.y, x3.z, x3.w};

        float4 a0 = {0.f,0.f,0.f,0.f}, a1 = a0, a2 = a0, a3 = a0;
        const float* Wg = W1 + g * D_ * H_ + half * 16;
#pragma unroll
        for (int d = 0; d < D_; ++d) {
            const float xd = xv[d];
            const float4* wr = (const float4*)(Wg + d * H_);
            const float4 w0 = wr[0], w1 = wr[1], w2 = wr[2], w3 = wr[3];
            a0.x = fmaf(xd, w0.x, a0.x); a0.y = fmaf(xd, w0.y, a0.y);
            a0.z = fmaf(xd, w0.z, a0.z); a0.w = fmaf(xd, w0.w, a0.w);
            a1.x = fmaf(xd, w1.x, a1.x); a1.y = fmaf(xd, w1.y, a1.y);
            a1.z = fmaf(xd, w1.z, a1.z); a1.w = fmaf(xd, w1.w, a1.w);
            a2.x = fmaf(xd, w2.x, a2.x); a2.y = fmaf(xd, w2.y, a2.y);
            a2.z = fmaf(xd, w2.z, a2.z); a2.w = fmaf(xd, w2.w, a2.w);
            a3.x = fmaf(xd, w3.x, a3.x); a3.y = fmaf(xd, w3.y, a3.y);
            a3.z = fmaf(xd, w3.z, a3.z); a3.w = fmaf(xd, w3.w, a3.w);
        }
        if (g == 0) {
            float4* dst = (float4*)&ai_lds[row * 32 + half * 16];
            dst[0] = a0; dst[1] = a1; dst[2] = a2; dst[3] = a3;
        } else {
            float* dst = &aj_lds[row * 33 + half * 16];
            dst[0]  = a0.x; dst[1]  = a0.y; dst[2]  = a0.z; dst[3]  = a0.w;
            dst[4]  = a1.x; dst[5]  = a1.y; dst[6]  = a1.z; dst[7]  = a1.w;
            dst[8]  = a2.x; dst[9]  = a2.y; dst[10] = a2.z; dst[11] = a2.w;
            dst[12] = a3.x; dst[13] = a3.y; dst[14] = a3.z; dst[15] = a3.w;
        }
    }

    // ---- Phase 1b: ae (dt embedding @ W1c + b1). ----
    if (!constpath) {
        for (int idx = tid; idx < (TAU_ + 1) * H_; idx += 256) {
            const int t2 = idx >> 5, h = idx & 31;
            float s = b1[h];
#pragma unroll
            for (int e = 0; e < EMB_; ++e)
                s = fmaf(dtt[t2 * EMB_ + e], W1[(2 * D_ + e) * H_ + h], s);
            ae_lds[t2 * 33 + h] = s;
        }
    } else if (tid < H_) {
        const int dtc = c0 ? 0 : TAU_;
        float s = b1[tid];
#pragma unroll
        for (int e = 0; e < EMB_; ++e)
            s = fmaf(dtt[dtc * EMB_ + e], W1[(2 * D_ + e) * H_ + tid], s);
        aec[tid] = s;
    }
    __syncthreads();

    // ---- Phase 2: per-lane column vector, then 16 rows per wave. ----
    float r[H_];
    {
        const float* ajr = &aj_lds[lane * 33];   // stride 33: conflict-free
#pragma unroll
        for (int h = 0; h < H_; ++h) r[h] = ajr[h];
    }
    if (constpath) {
#pragma unroll
        for (int h = 0; h < H_; ++h) r[h] += aec[h];   // broadcast reads
    }

    const float b2 = *b2p;
    const int  iw  = w * 16;
    float* outb = out + ((size_t)b) * L_ * L_ + ((size_t)(i0 + iw)) * L_ + j;

    if (constpath) {
        const float pc = b2 - 0.2f * (c0 ? 0.f : (float)TAU_);
        for (int ii = 0; ii < 16; ii += 2) {
            const float4* ar0 = (const float4*)&ai_lds[(iw + ii + 0) * 32];
            const float4* ar1 = (const float4*)&ai_lds[(iw + ii + 1) * 32];
            float a0x = 0.f, a0y = 0.f, a1x = 0.f, a1y = 0.f;
#pragma unroll
            for (int q = 0; q < 8; ++q) {
                const float4 v0 = ar0[q], v1 = ar1[q];
                const int h = q * 4;
                const float w0 = W2[h], w1 = W2[h + 1], w2 = W2[h + 2], w3 = W2[h + 3];
                a0x = fmaf(fmaxf(v0.x + r[h + 0], 0.f), w0, a0x);
                a0y = fmaf(fmaxf(v0.y + r[h + 1], 0.f), w1, a0y);
                a0x = fmaf(fmaxf(v0.z + r[h + 2], 0.f), w2, a0x);
                a0y = fmaf(fmaxf(v0.w + r[h + 3], 0.f), w3, a0y);
                a1x = fmaf(fmaxf(v1.x + r[h + 0], 0.f), w0, a1x);
                a1y = fmaf(fmaxf(v1.y + r[h + 1], 0.f), w1, a1y);
                a1x = fmaf(fmaxf(v1.z + r[h + 2], 0.f), w2, a1x);
                a1y = fmaf(fmaxf(v1.w + r[h + 3], 0.f), w3, a1y);
            }
            __builtin_nontemporal_store(a0x + a0y + pc, outb + (size_t)(ii + 0) * L_);
            __builtin_nontemporal_store(a1x + a1y + pc, outb + (size_t)(ii + 1) * L_);
        }
    } else {
        for (int ii = 0; ii < 16; ++ii) {
            const int i  = i0 + iw + ii;
            const int d  = i - j;
            const int dt = d < 0 ? 0 : (d > TAU_ ? TAU_ : d);
            const float* aeL = &ae_lds[dt * 33];      // 2-way worst case: free
            const float4* ar = (const float4*)&ai_lds[(iw + ii) * 32];
            float accx = 0.f, accy = 0.f;
#pragma unroll
            for (int q = 0; q < 8; ++q) {
                const float4 v = ar[q];
                const int h = q * 4;
                accx = fmaf(fmaxf(v.x + r[h + 0] + aeL[h + 0], 0.f), W2[h + 0], accx);
                accy = fmaf(fmaxf(v.y + r[h + 1] + aeL[h + 1], 0.f), W2[h + 1], accy);
                accx = fmaf(fmaxf(v.z + r[h + 2] + aeL[h + 2], 0.f), W2[h + 2], accx);
                accy = fmaf(fmaxf(v.w + r[h + 3] + aeL[h + 3], 0.f), W2[h + 3], accy);
            }
            __builtin_nontemporal_store(accx + accy + b2 - 0.2f * (float)dt,
                                        outb + (size_t)ii * L_);
        }
    }
}

extern "C" void kernel_launch(void* const* d_in, const int* in_sizes, int n_in,
                              void* d_out, int out_size, void* d_ws, size_t ws_size,
                              hipStream_t stream) {
    const float* x   = (const float*)d_in[0];
    const float* dtt = (const float*)d_in[1];
    const float* W1  = (const float*)d_in[2];
    const float* b1  = (const float*)d_in[3];
    const float* W2  = (const float*)d_in[4];
    const float* b2  = (const float*)d_in[5];
    float* out = (float*)d_out;

    dim3 grid(L_ / 64, L_ / 64, B_);
    hipLaunchKernelGGL(fused_bias_kernel, grid, dim3(256), 0, stream,
                       x, dtt, W1, b1, W2, b2, out);
}